// Round 9
// baseline (1930.544 us; speedup 1.0000x reference)
//
#include <hip/hip_runtime.h>
#include <math.h>

using u16 = unsigned short;
using u32 = unsigned int;
typedef _Float16 f16x8 __attribute__((ext_vector_type(8)));
typedef float    f32x4 __attribute__((ext_vector_type(4)));

union F16U { _Float16 h; u16 u; };
__device__ __forceinline__ u16 f2h(float f) { F16U x; x.h = (_Float16)f; return x.u; }
__device__ __forceinline__ float h2f(u16 v) { F16U x; x.u = v; return (float)x.h; }

// async 16B global->LDS (linear LDS dest = wave base + lane*16; per-lane global src)
__device__ __forceinline__ void gl16(const void* g, void* l) {
  __builtin_amdgcn_global_load_lds((const __attribute__((address_space(1))) void*)g,
                                   (__attribute__((address_space(3))) void*)l, 16, 0, 0);
}

// ---------------- producers ----------------

// weights permuted to [co][tap*128+ci], f16
__global__ void k_wperm(const float* __restrict__ w, u16* __restrict__ Wp) {
  int idx = blockIdx.x * 256 + threadIdx.x;
  if (idx < 147456) {
    int co = idx / 1152, r = idx - co * 1152, tap = r >> 7, ci = r & 127;
    Wp[idx] = f2h(w[((size_t)co * 128 + ci) * 9 + tap]);
  }
}

// strided (::2) slices, split into hi/lo f16, stored TRANSPOSED [p][c]
__global__ void k_extract(const float* __restrict__ fi, const float* __restrict__ bi,
                          u16* __restrict__ fh, u16* __restrict__ fl,
                          u16* __restrict__ bh, u16* __restrict__ bl) {
  __shared__ u16 lt[4][64][136];
  int ph = blockIdx.x, t = threadIdx.x;
  for (int it = 0; it < 32; ++it) {
    int idx = it * 256 + t;                 // c*64 + pw
    int c = idx >> 6, pw = idx & 63;
    int src = c * 16384 + (2 * ph) * 128 + 2 * pw;
    float vf = fi[src], vb = bi[src];
    u16 fhi = f2h(vf), flo = f2h(vf - h2f(fhi));
    u16 bhi = f2h(vb), blo = f2h(vb - h2f(bhi));
    lt[0][pw][c] = fhi; lt[1][pw][c] = flo; lt[2][pw][c] = bhi; lt[3][pw][c] = blo;
  }
  __syncthreads();
  for (int it = 0; it < 16; ++it) {
    int g = it * 256 + t;                   // 4 arrays * 64 pw * 16 granules
    int arr = g >> 10, rem = g & 1023, pw = rem >> 4, slot = rem & 15;
    uint4 v = *(const uint4*)&lt[arr][pw][slot * 8];
    u16* o = (arr == 0) ? fh : (arr == 1) ? fl : (arr == 2) ? bh : bl;
    *(uint4*)&o[(size_t)(ph * 64 + pw) * 128 + slot * 8] = v;
  }
}

// norm[l] = ||3x3x128 bs-patch|| from hi/lo transposed arrays; one wave per l
__global__ void k_norm(const u16* __restrict__ bh, const u16* __restrict__ bl,
                       float* __restrict__ nrm) {
  int wid = threadIdx.x >> 6, lane = threadIdx.x & 63;
  int l = blockIdx.x * 4 + wid;
  int lh = l >> 6, lw = l & 63;
  float s = 0.f;
#pragma unroll
  for (int dh = -1; dh <= 1; ++dh)
#pragma unroll
    for (int dw = -1; dw <= 1; ++dw) {
      int y = lh + dh, x = lw + dw;
      if ((u32)y < 64u && (u32)x < 64u) {
        int p = y * 64 + x;
        u32 h2 = *(const u32*)&bh[(size_t)p * 128 + lane * 2];
        u32 l2 = *(const u32*)&bl[(size_t)p * 128 + lane * 2];
        float v0 = h2f((u16)h2) + h2f((u16)l2);
        float v1 = h2f((u16)(h2 >> 16)) + h2f((u16)(l2 >> 16));
        s += v0 * v0 + v1 * v1;
      }
    }
#pragma unroll
  for (int off = 32; off; off >>= 1) s += __shfl_xor(s, off);
  if (lane == 0) nrm[l] = sqrtf(s);
}

// ---------------- R GEMM: split-f16 MFMA; DIAGONAL-layout output ----------------
// writes Rd[(q-l)&4095][l] = R[q][l]
__global__ __launch_bounds__(256) void k_rgemm(const u16* __restrict__ fh, const u16* __restrict__ fl,
                                               const u16* __restrict__ bh, const u16* __restrict__ bl,
                                               float* __restrict__ C) {
  __shared__ u16 lds[4 * 128 * 64];          // 64KB: staging during K-loop, fp32 tile in epilogue
  u16* Ah = lds; u16* Al = lds + 8192; u16* Bh = lds + 16384; u16* Bl = lds + 24576;
  int t = threadIdx.x, lane = t & 63, wid = t >> 6;
  int wm = (wid >> 1) * 64, wn = (wid & 1) * 64;
  int fr = lane & 15, kb = lane >> 4;
  int b = blockIdx.x;
  int xcd = b & 7, r = b >> 3;
  int by = xcd * 4 + (r & 3), bx = r >> 2;
  int q0 = by * 128, l0 = bx * 128;
  f32x4 acc[4][4] = {};
  for (int kt = 0; kt < 128; kt += 64) {
#pragma unroll
    for (int j = 0; j < 4; ++j) {
      int g = wid * 256 + j * 64 + lane;
      int row = g >> 3, s = (g & 7) ^ (row & 7);
      int co = kt + s * 8;
      size_t ldso = (size_t)(wid * 256 + j * 64) * 8;
      gl16(&fh[(size_t)(q0 + row) * 128 + co], Ah + ldso);
      gl16(&fl[(size_t)(q0 + row) * 128 + co], Al + ldso);
      gl16(&bh[(size_t)(l0 + row) * 128 + co], Bh + ldso);
      gl16(&bl[(size_t)(l0 + row) * 128 + co], Bl + ldso);
    }
    __syncthreads();
#pragma unroll
    for (int kf = 0; kf < 2; ++kf) {
      f16x8 ah[4], al4[4], bh4[4], bl4[4];
#pragma unroll
      for (int mi = 0; mi < 4; ++mi) {
        int row = wm + mi * 16 + fr;
        int off = row * 64 + ((kf * 4 + kb) ^ (row & 7)) * 8;
        ah[mi] = *(const f16x8*)&Ah[off];
        al4[mi] = *(const f16x8*)&Al[off];
      }
#pragma unroll
      for (int ni = 0; ni < 4; ++ni) {
        int row = wn + ni * 16 + fr;
        int off = row * 64 + ((kf * 4 + kb) ^ (row & 7)) * 8;
        bh4[ni] = *(const f16x8*)&Bh[off];
        bl4[ni] = *(const f16x8*)&Bl[off];
      }
#pragma unroll
      for (int mi = 0; mi < 4; ++mi)
#pragma unroll
        for (int ni = 0; ni < 4; ++ni) {
          acc[mi][ni] = __builtin_amdgcn_mfma_f32_16x16x32_f16(ah[mi], bh4[ni], acc[mi][ni], 0, 0, 0);
          acc[mi][ni] = __builtin_amdgcn_mfma_f32_16x16x32_f16(ah[mi], bl4[ni], acc[mi][ni], 0, 0, 0);
          acc[mi][ni] = __builtin_amdgcn_mfma_f32_16x16x32_f16(al4[mi], bh4[ni], acc[mi][ni], 0, 0, 0);
        }
    }
    __syncthreads();
  }
  // stage tile to LDS as fp32 [128][128]
  float* TC = (float*)lds;
#pragma unroll
  for (int mi = 0; mi < 4; ++mi) {
    int qr = wm + mi * 16 + kb * 4;
#pragma unroll
    for (int ni = 0; ni < 4; ++ni) {
      int lc = wn + ni * 16 + fr;
#pragma unroll
      for (int r2 = 0; r2 < 4; ++r2)
        TC[(qr + r2) * 128 + lc] = acc[mi][ni][r2];
    }
  }
  __syncthreads();
  // write 255 diagonal segments (contiguous in l) to Rd; 64 diagonals per wave
  int dq0l0 = q0 - l0;
  for (int dd = wid * 64; dd < wid * 64 + 64; ++dd) {
    if (dd >= 255) break;
    int d = dd - 127;
    int jst = d < 0 ? -d : 0;
    int len = 128 - (d < 0 ? -d : d);
    int drow = (dq0l0 + d) & 4095;
#pragma unroll
    for (int ro = 0; ro < 2; ++ro) {
      int j = jst + ro * 64 + lane;
      if (j < jst + len)
        C[(size_t)drow * 4096 + l0 + j] = TC[(j + d) * 128 + j];
    }
  }
}

// ---------------- passA on diagonal layout: 1-D 9-tap row stencil ----------------
// Yd[drow][u] = (sum of masked taps Rd[drow][u+s]) / max(nrm[u],1e-4)
__global__ __launch_bounds__(256) void k_passA(const float* __restrict__ Rd, const float* __restrict__ nrm,
                                               float* __restrict__ Yd) {
  int tid = blockIdx.x * 256 + threadIdx.x;      // 8192 blocks
  int drow = tid >> 9;
  int u0 = (tid & 511) * 8;
  float buf[3][16];
#pragma unroll
  for (int c = 0; c < 3; ++c) {
    int base = drow * 4096 + u0 + (c - 1) * 64 - 4;
#pragma unroll
    for (int kk = 0; kk < 4; ++kk) {
      int a = base + kk * 4;
      a = a < 0 ? 0 : (a > 16777212 ? 16777212 : a);
      *(float4*)&buf[c][kk * 4] = *(const float4*)&Rd[a];
    }
  }
  float4 nv0 = *(const float4*)&nrm[u0];
  float4 nv1 = *(const float4*)&nrm[u0 + 4];
  float nvv[8] = {nv0.x, nv0.y, nv0.z, nv0.w, nv1.x, nv1.y, nv1.z, nv1.w};
  float out[8];
#pragma unroll
  for (int e = 0; e < 8; ++e) {
    int l = u0 + e;
    int q = (drow + l) & 4095;
    int lh = l >> 6, lw = l & 63, qh = q >> 6, qw = q & 63;
    float a = 0.f;
#pragma unroll
    for (int c = 0; c < 3; ++c) {
      bool mh = ((u32)(qh + c - 1) < 64u) && ((u32)(lh + c - 1) < 64u);
#pragma unroll
      for (int d = 0; d < 3; ++d) {
        bool mw = ((u32)(qw + d - 1) < 64u) && ((u32)(lw + d - 1) < 64u);
        if (mh && mw) a += buf[c][e + d + 3];
      }
    }
    out[e] = a / fmaxf(nvv[e], 1e-4f);
  }
  *(float4*)&Yd[(size_t)drow * 4096 + u0] = make_float4(out[0], out[1], out[2], out[3]);
  *(float4*)&Yd[(size_t)drow * 4096 + u0 + 4] = make_float4(out[4], out[5], out[6], out[7]);
}

// ---------------- pbsm on diagonal layout -> row-major fp32 S ----------------
// Branch-free fast path (unrolled, registers) + separate edge-fixup loop; ST padded [64][66].
__global__ __launch_bounds__(256) void k_pbsm(const float* __restrict__ Yd, float* __restrict__ S) {
  __shared__ float ST[64][66];
  int b = blockIdx.x;
  int d0 = (b >> 6) * 64, u0 = (b & 63) * 64;
  int t = threadIdx.x;
  int dl = t >> 2, us = (t & 3) * 16;
  int drow = d0 + dl;
  int ub = u0 + us;
  int lh = u0 >> 6;
  bool lhok = (lh >= 2 && lh <= 61);
  // windows: 3 clusters x 24 floats (aligned float4 loads, clamped)
  float w[3][24];
#pragma unroll
  for (int c = 0; c < 3; ++c) {
    int base = drow * 4096 + ub + (c - 1) * 64 - 4;
#pragma unroll
    for (int kk = 0; kk < 6; ++kk) {
      int a = base + kk * 4;
      a = a < 0 ? 0 : (a > 16777212 ? 16777212 : a);
      *(float4*)&w[c][kk * 4] = *(const float4*)&Yd[a];
    }
  }
  // branch-free fast sums -> ST (guaranteed unroll: tiny body, no branches)
#pragma unroll
  for (int e = 0; e < 16; ++e) {
    ST[dl][us + e] = (w[0][e + 3] + w[0][e + 4] + w[0][e + 5])
                   + (w[1][e + 3] + w[1][e + 4] + w[1][e + 5])
                   + (w[2][e + 3] + w[2][e + 4] + w[2][e + 5]);
  }
  // edge fixup: only threads whose 16-element span touches a non-interior q (or edge lh)
  int qa = (drow + ub) & 4095, qb = (drow + ub + 15) & 4095;
  bool anyedge = !lhok || (qa >> 6) < 2 || (qa >> 6) > 61 || (qb >> 6) < 2 || (qb >> 6) > 61 ||
                 (qa + 15 != qb);
  if (anyedge) {
    for (int e = 0; e < 16; ++e) {
      int l = ub + e;
      int q = (drow + l) & 4095;
      int qh = q >> 6;
      if (!(lhok && qh >= 2 && qh <= 61)) {
        // exact reference flat/permuted path
        int pl = ((l & 63) << 6) | (l >> 6);
        int pq = ((q & 63) << 6) | (q >> 6);
        float a = 0.f;
        for (int e2 = -1; e2 <= 1; ++e2) {
          int pa = pl + e2, pb = pq + e2;
          if ((u32)pa < 4096u && (u32)pb < 4096u) {
            int aa0 = ((pa & 63) << 6) | (pa >> 6);
            int bb0 = ((pb & 63) << 6) | (pb >> 6);
            for (int e1 = -1; e1 <= 1; ++e1) {
              int aa = aa0 + e1, bb = bb0 + e1;
              if ((u32)aa < 4096u && (u32)bb < 4096u)
                a += Yd[(size_t)((bb - aa) & 4095) * 4096 + aa];
            }
          }
        }
        ST[dl][us + e] = a;
      }
    }
  }
  __syncthreads();
  // write tile to S row-major: for each j = dl+ul, lanes sweep the segment (coalesced)
  int w2 = t >> 6, lane = t & 63;
  for (int jj = 0; jj < 32; ++jj) {
    int j = w2 * 32 + jj;
    if (j >= 127) break;
    int jm = j < 63 ? j : 63;
    int dd = jm - lane;
    int ul = j - dd;
    if (dd >= 0 && ul < 64) {
      int q = (d0 + u0 + j) & 4095;
      S[(size_t)q * 4096 + u0 + ul] = ST[dd][ul];
    }
  }
}

// row softmax over l (SCALE=10), vectorized, fp32 S -> f16 att
__global__ __launch_bounds__(256) void k_softmax(const float* __restrict__ S, u16* __restrict__ att) {
  int q = blockIdx.x, t = threadIdx.x;
  const float* row = S + (size_t)q * 4096;
  float4 v[4];
  float m = -3.4e38f;
#pragma unroll
  for (int i = 0; i < 4; ++i) {
    v[i] = *(const float4*)&row[i * 1024 + t * 4];
    m = fmaxf(m, fmaxf(fmaxf(v[i].x, v[i].y), fmaxf(v[i].z, v[i].w)));
  }
#pragma unroll
  for (int off = 32; off; off >>= 1) m = fmaxf(m, __shfl_xor(m, off));
  __shared__ float redm[4], reds[4];
  int wid = t >> 6, lane = t & 63;
  if (lane == 0) redm[wid] = m;
  __syncthreads();
  m = fmaxf(fmaxf(redm[0], redm[1]), fmaxf(redm[2], redm[3]));
  float s = 0.f;
#pragma unroll
  for (int i = 0; i < 4; ++i) {
    v[i].x = expf(10.f * (v[i].x - m)); v[i].y = expf(10.f * (v[i].y - m));
    v[i].z = expf(10.f * (v[i].z - m)); v[i].w = expf(10.f * (v[i].w - m));
    s += v[i].x + v[i].y + v[i].z + v[i].w;
  }
#pragma unroll
  for (int off = 32; off; off >>= 1) s += __shfl_xor(s, off);
  if (lane == 0) reds[wid] = s;
  __syncthreads();
  s = reds[0] + reds[1] + reds[2] + reds[3];
  float inv = 1.f / s;
  u16* arow = att + (size_t)q * 4096;
#pragma unroll
  for (int i = 0; i < 4; ++i) {
    union { u16 h[4]; uint2 u; } pk;
    pk.h[0] = f2h(v[i].x * inv); pk.h[1] = f2h(v[i].y * inv);
    pk.h[2] = f2h(v[i].z * inv); pk.h[3] = f2h(v[i].w * inv);
    *(uint2*)&arow[i * 1024 + t * 4] = pk.u;
  }
}

// RWt[m][l] = raw_w[l, c,i,j] (m = c*16+i*4+j), f16; 4 l per thread
__global__ void k_rwt(const float* __restrict__ bi, u16* __restrict__ RWt) {
  int tid = blockIdx.x * 256 + threadIdx.x;       // m*1024 + l/4
  int m = tid >> 10, lq = (tid & 1023) * 4;
  int c = m >> 4, i = (m >> 2) & 3, j = m & 3;
  int y = 2 * (lq >> 6) - 1 + i;
  union { u16 h[4]; uint2 u; } pk;
#pragma unroll
  for (int e = 0; e < 4; ++e) {
    int x = 2 * ((lq + e) & 63) - 1 + j;
    float v = 0.f;
    if ((u32)y < 128u && (u32)x < 128u) v = bi[c * 16384 + y * 128 + x];
    pk.h[e] = f2h(v);
  }
  *(uint2*)&RWt[(size_t)m * 4096 + lq] = pk.u;
}

// ---------------- PV GEMM: double-buffered gl16 + XCD m-panel swizzle ----------------
__global__ __launch_bounds__(256) void k_gemm_pv(const u16* __restrict__ A, const u16* __restrict__ Bt,
                                                 float* __restrict__ C) {
  __shared__ u16 lds[2 * 16384];
  int t = threadIdx.x, lane = t & 63, wid = t >> 6;
  int wm = (wid >> 1) * 64, wn = (wid & 1) * 64;
  int fr = lane & 15, kb = lane >> 4;
  int bid = blockIdx.x;
  int my = (bid & 7) * 4 + ((bid >> 3) & 3);
  int nx = bid >> 5;
  int m0 = my * 128, n0 = nx * 128;
  f32x4 acc[4][4] = {};
#define STAGE(buf, kt)                                                                  \
  {                                                                                     \
    u16* lA = lds + (buf) * 16384;                                                      \
    u16* lB = lA + 8192;                                                                \
    _Pragma("unroll")                                                                   \
    for (int j = 0; j < 4; ++j) {                                                       \
      int g = wid * 256 + j * 64 + lane;                                                \
      int row = g >> 3, sw = (g & 7) ^ (row & 7);                                       \
      size_t ldso = (size_t)(wid * 256 + j * 64) * 8;                                   \
      gl16(&A[(size_t)(m0 + row) * 4096 + (kt) + sw * 8], lA + ldso);                   \
      gl16(&Bt[(size_t)(n0 + row) * 4096 + (kt) + sw * 8], lB + ldso);                  \
    }                                                                                   \
  }
  STAGE(0, 0)
  __syncthreads();
  int cur = 0;
  for (int kt = 0; kt < 4096; kt += 64) {
    if (kt + 64 < 4096) STAGE(cur ^ 1, kt + 64)
    u16* la = lds + cur * 16384;
    u16* lb = la + 8192;
#pragma unroll
    for (int ks = 0; ks < 2; ++ks) {
      f16x8 af[4], bfr[4];
#pragma unroll
      for (int mi = 0; mi < 4; ++mi) {
        int row = wm + mi * 16 + fr;
        af[mi] = *(const f16x8*)&la[row * 64 + ((ks * 32 + kb * 8) ^ ((row & 7) << 3))];
      }
#pragma unroll
      for (int ni = 0; ni < 4; ++ni) {
        int row = wn + ni * 16 + fr;
        bfr[ni] = *(const f16x8*)&lb[row * 64 + ((ks * 32 + kb * 8) ^ ((row & 7) << 3))];
      }
#pragma unroll
      for (int mi = 0; mi < 4; ++mi)
#pragma unroll
        for (int ni = 0; ni < 4; ++ni)
          acc[mi][ni] = __builtin_amdgcn_mfma_f32_16x16x32_f16(af[mi], bfr[ni], acc[mi][ni], 0, 0, 0);
    }
    __syncthreads();
    cur ^= 1;
  }
#undef STAGE
#pragma unroll
  for (int mi = 0; mi < 4; ++mi) {
    int mr = m0 + wm + mi * 16 + kb * 4;
#pragma unroll
    for (int ni = 0; ni < 4; ++ni) {
      int nc = n0 + wn + ni * 16 + fr;
#pragma unroll
      for (int r = 0; r < 4; ++r)
        C[(size_t)(mr + r) * 2048 + nc] = acc[mi][ni][r];
    }
  }
}

// stride-2 overlap-add of 4x4 patches, /4 -> HWC f16; XCD-pinned to match gemm_pv m-panels
__global__ void k_overlap(const float* __restrict__ O, u16* __restrict__ Yh) {
  int b = blockIdx.x;
  int xcd = b & 7, r = b >> 3;
  int oypair = xcd * 8 + (r & 7);
  int c = r >> 3;
  int t = threadIdx.x;
  int idx = c * 16384 + oypair * 256 + t;
  int ox = idx & 127, oy = (idx & 16383) >> 7;
  int py = oy + 1, px = ox + 1;
  float s = 0.f;
#pragma unroll
  for (int di = 0; di < 2; ++di) {
    int i = (py & 1) + 2 * di;
    int hs = (py - i) >> 1;
    if ((u32)hs >= 64u) continue;
#pragma unroll
    for (int dj = 0; dj < 2; ++dj) {
      int j = (px & 1) + 2 * dj;
      int wsx = (px - j) >> 1;
      if ((u32)wsx >= 64u) continue;
      s += O[(size_t)(hs * 64 + wsx) * 2048 + c * 16 + i * 4 + j];
    }
  }
  Yh[((size_t)oy * 128 + ox) * 128 + c] = f2h(0.25f * s);
}

// ---------------- conv: HWC f16 in, implicit GEMM, global_load_lds ----------------
template<int OUT_F16>
__global__ __launch_bounds__(256) void k_conv(const u16* __restrict__ In, const u16* __restrict__ Wp,
                                              const float* __restrict__ bias, void* __restrict__ out_,
                                              const u16* __restrict__ zg) {
  __shared__ u16 lds[2 * 128 * 64];
  u16* la = lds; u16* lb = lds + 8192;
  int t = threadIdx.x, lane = t & 63, wid = t >> 6;
  int wm = (wid >> 1) * 64, wn = (wid & 1) * 64;
  int fr = lane & 15, kb = lane >> 4;
  int yrow = blockIdx.x, bidx = blockIdx.y;
  const u16* inH = In + (size_t)bidx * 2097152;
  f32x4 acc[4][4] = {};
  for (int step = 0; step < 18; ++step) {
    int tap = step >> 1, ci0 = (step & 1) * 64;
    int dy = tap / 3, dx = tap - 3 * (tap / 3);
    int y = yrow + dy - 1;
#pragma unroll
    for (int j = 0; j < 4; ++j) {
      int g = wid * 256 + j * 64 + lane;
      int row = g >> 3, s = (g & 7) ^ (row & 7);
      size_t ldso = (size_t)(wid * 256 + j * 64) * 8;
      gl16(&Wp[(size_t)row * 1152 + step * 64 + s * 8], la + ldso);
      int xx = row + dx - 1;
      const u16* src = ((u32)y < 128u && (u32)xx < 128u)
                         ? &inH[((size_t)y * 128 + xx) * 128 + ci0 + s * 8] : zg;
      gl16(src, lb + ldso);
    }
    __syncthreads();
#pragma unroll
    for (int ks = 0; ks < 2; ++ks) {
      f16x8 af[4], bfr[4];
#pragma unroll
      for (int mi = 0; mi < 4; ++mi) {
        int row = wm + mi * 16 + fr;
        af[mi] = *(const f16x8*)&la[row * 64 + ((ks * 32 + kb * 8) ^ ((row & 7) << 3))];
      }
#pragma unroll
      for (int ni = 0; ni < 4; ++ni) {
        int row = wn + ni * 16 + fr;
        bfr[ni] = *(const f16x8*)&lb[row * 64 + ((ks * 32 + kb * 8) ^ ((row & 7) << 3))];
      }
#pragma unroll
      for (int mi = 0; mi < 4; ++mi)
#pragma unroll
        for (int ni = 0; ni < 4; ++ni)
          acc[mi][ni] = __builtin_amdgcn_mfma_f32_16x16x32_f16(af[mi], bfr[ni], acc[mi][ni], 0, 0, 0);
    }
    __syncthreads();
  }
#pragma unroll
  for (int mi = 0; mi < 4; ++mi) {
    int co = wm + mi * 16 + kb * 4;
#pragma unroll
    for (int ni = 0; ni < 4; ++ni) {
      int x = wn + ni * 16 + fr;
      if (OUT_F16) {
        union { u16 h[4]; uint2 v; } pk;
#pragma unroll
        for (int r = 0; r < 4; ++r) {
          float val = acc[mi][ni][r] + bias[co + r];
          val = val > 0.f ? val : expm1f(val);
          pk.h[r] = f2h(val);
        }
        u16* oH = (u16*)out_ + (size_t)bidx * 2097152;
        *(uint2*)&oH[((size_t)yrow * 128 + x) * 128 + co] = pk.v;
      } else {
        float* oF = (float*)out_ + (size_t)bidx * 2097152;
#pragma unroll
        for (int r = 0; r < 4; ++r) {
          float val = acc[mi][ni][r] + bias[co + r];
          val = val > 0.f ? val : expm1f(val);
          oF[(size_t)(co + r) * 16384 + yrow * 128 + x] = val;
        }
      }
    }
  }
}

// ---------------- host ----------------

extern "C" void kernel_launch(void* const* d_in, const int* in_sizes, int n_in,
                              void* d_out, int out_size, void* d_ws, size_t ws_size,
                              hipStream_t stream) {
  const float* f  = (const float*)d_in[0];
  const float* b  = (const float*)d_in[1];
  const float* w1 = (const float*)d_in[2];
  const float* b1 = (const float*)d_in[3];
  const float* w2 = (const float*)d_in[4];
  const float* b2 = (const float*)d_in[5];
  float* out = (float*)d_out;
  char* ws = (char*)d_ws;

  // workspace layout (155,795,456 B total)
  float* S0   = (float*)(ws);                       // 64MB: Rd -> S (scores) -> O [0,32) / Z1h
  float* S1   = (float*)(ws + 67108864);            // 64MB: Yd -> att [0,32) + RWt [32,48)
  u16*   fsTh = (u16*)(ws + 134217728);             // 1,048,576
  u16*   fsTl = (u16*)(ws + 135266304);             // 1,048,576
  u16*   bsTh = (u16*)(ws + 136314880);             // 1,048,576
  u16*   bsTl = (u16*)(ws + 137363456);             // 1,048,576
  float* nrm  = (float*)(ws + 138412032);           // 16,384
  u16*   Yh   = (u16*)(ws + 138428416);             // 16,777,216 (4 batches HWC f16)
  u16*   Wp1  = (u16*)(ws + 155205632);             // 294,912
  u16*   Wp2  = (u16*)(ws + 155500544);             // 294,912 -> 155,795,456
  float* Rd   = S0;                                 // diag R, full 64MB
  float* Yd   = S1;                                 // diag Y0, full 64MB
  float* Ssc  = S0;                                 // fp32 scores, overlays Rd (dead)
  u16*   att  = (u16*)S1;                           // [0,32MB) of S1 (Yd dead after pbsm)
  u16*   RWt  = (u16*)(ws + 67108864 + 33554432);   // [32,48MB) of S1
  float* O    = S0;                                 // [0,32MB) of S0 (Ssc dead after softmax)
  u16*   Z1h  = (u16*)S0;                           // convs after loop
  u16*   zg   = (u16*)(ws + 50331648);              // 256 B zero guard (memset after last producer)

  k_wperm<<<576, 256, 0, stream>>>(w1, Wp1);
  k_wperm<<<576, 256, 0, stream>>>(w2, Wp2);

  for (int i = 0; i < 4; ++i) {
    const float* fb = f + (size_t)i * 2097152;
    const float* bb = b + (size_t)i * 2097152;
    k_extract<<<64, 256, 0, stream>>>(fb, bb, fsTh, fsTl, bsTh, bsTl);
    k_norm<<<1024, 256, 0, stream>>>(bsTh, bsTl, nrm);
    k_rgemm<<<1024, 256, 0, stream>>>(fsTh, fsTl, bsTh, bsTl, Rd);
    k_passA<<<8192, 256, 0, stream>>>(Rd, nrm, Yd);
    k_pbsm<<<4096, 256, 0, stream>>>(Yd, Ssc);
    k_softmax<<<4096, 256, 0, stream>>>(Ssc, att);
    k_rwt<<<8192, 256, 0, stream>>>(bb, RWt);
    k_gemm_pv<<<512, 256, 0, stream>>>(att, RWt, O);
    k_overlap<<<8192, 256, 0, stream>>>(O, Yh + (size_t)i * 2097152);
  }

  hipMemsetAsync(zg, 0, 256, stream);
  k_conv<1><<<dim3(128, 4), 256, 0, stream>>>(Yh, Wp1, b1, Z1h, zg);
  k_conv<0><<<dim3(128, 4), 256, 0, stream>>>(Z1h, Wp2, b2, out, zg);

  (void)in_sizes; (void)n_in; (void)out_size; (void)ws_size;
}

// Round 10
// 1302.900 us; speedup vs baseline: 1.4817x; 1.4817x over previous
//
#include <hip/hip_runtime.h>
#include <math.h>

using u16 = unsigned short;
using u32 = unsigned int;
typedef _Float16 f16x8 __attribute__((ext_vector_type(8)));
typedef float    f32x4 __attribute__((ext_vector_type(4)));

union F16U { _Float16 h; u16 u; };
__device__ __forceinline__ u16 f2h(float f) { F16U x; x.h = (_Float16)f; return x.u; }
__device__ __forceinline__ float h2f(u16 v) { F16U x; x.u = v; return (float)x.h; }

// async 16B global->LDS (linear LDS dest = wave base + lane*16; per-lane global src)
__device__ __forceinline__ void gl16(const void* g, void* l) {
  __builtin_amdgcn_global_load_lds((const __attribute__((address_space(1))) void*)g,
                                   (__attribute__((address_space(3))) void*)l, 16, 0, 0);
}

// ---------------- producers ----------------

// weights permuted to [co][tap*128+ci], f16
__global__ void k_wperm(const float* __restrict__ w, u16* __restrict__ Wp) {
  int idx = blockIdx.x * 256 + threadIdx.x;
  if (idx < 147456) {
    int co = idx / 1152, r = idx - co * 1152, tap = r >> 7, ci = r & 127;
    Wp[idx] = f2h(w[((size_t)co * 128 + ci) * 9 + tap]);
  }
}

// strided (::2) slices, split into hi/lo f16, stored TRANSPOSED [p][c]
__global__ void k_extract(const float* __restrict__ fi, const float* __restrict__ bi,
                          u16* __restrict__ fh, u16* __restrict__ fl,
                          u16* __restrict__ bh, u16* __restrict__ bl) {
  __shared__ u16 lt[4][64][136];
  int ph = blockIdx.x, t = threadIdx.x;
  for (int it = 0; it < 32; ++it) {
    int idx = it * 256 + t;                 // c*64 + pw
    int c = idx >> 6, pw = idx & 63;
    int src = c * 16384 + (2 * ph) * 128 + 2 * pw;
    float vf = fi[src], vb = bi[src];
    u16 fhi = f2h(vf), flo = f2h(vf - h2f(fhi));
    u16 bhi = f2h(vb), blo = f2h(vb - h2f(bhi));
    lt[0][pw][c] = fhi; lt[1][pw][c] = flo; lt[2][pw][c] = bhi; lt[3][pw][c] = blo;
  }
  __syncthreads();
  for (int it = 0; it < 16; ++it) {
    int g = it * 256 + t;                   // 4 arrays * 64 pw * 16 granules
    int arr = g >> 10, rem = g & 1023, pw = rem >> 4, slot = rem & 15;
    uint4 v = *(const uint4*)&lt[arr][pw][slot * 8];
    u16* o = (arr == 0) ? fh : (arr == 1) ? fl : (arr == 2) ? bh : bl;
    *(uint4*)&o[(size_t)(ph * 64 + pw) * 128 + slot * 8] = v;
  }
}

// norm[l] = ||3x3x128 bs-patch|| from hi/lo transposed arrays; one wave per l
__global__ void k_norm(const u16* __restrict__ bh, const u16* __restrict__ bl,
                       float* __restrict__ nrm) {
  int wid = threadIdx.x >> 6, lane = threadIdx.x & 63;
  int l = blockIdx.x * 4 + wid;
  int lh = l >> 6, lw = l & 63;
  float s = 0.f;
#pragma unroll
  for (int dh = -1; dh <= 1; ++dh)
#pragma unroll
    for (int dw = -1; dw <= 1; ++dw) {
      int y = lh + dh, x = lw + dw;
      if ((u32)y < 64u && (u32)x < 64u) {
        int p = y * 64 + x;
        u32 h2 = *(const u32*)&bh[(size_t)p * 128 + lane * 2];
        u32 l2 = *(const u32*)&bl[(size_t)p * 128 + lane * 2];
        float v0 = h2f((u16)h2) + h2f((u16)l2);
        float v1 = h2f((u16)(h2 >> 16)) + h2f((u16)(l2 >> 16));
        s += v0 * v0 + v1 * v1;
      }
    }
#pragma unroll
  for (int off = 32; off; off >>= 1) s += __shfl_xor(s, off);
  if (lane == 0) nrm[l] = sqrtf(s);
}

// ---------------- R GEMM: split-f16 MFMA; DIAGONAL-layout output ----------------
// writes Rd[(q-l)&4095][l] = R[q][l]
__global__ __launch_bounds__(256) void k_rgemm(const u16* __restrict__ fh, const u16* __restrict__ fl,
                                               const u16* __restrict__ bh, const u16* __restrict__ bl,
                                               float* __restrict__ C) {
  __shared__ u16 lds[4 * 128 * 64];          // 64KB: staging during K-loop, fp32 tile in epilogue
  u16* Ah = lds; u16* Al = lds + 8192; u16* Bh = lds + 16384; u16* Bl = lds + 24576;
  int t = threadIdx.x, lane = t & 63, wid = t >> 6;
  int wm = (wid >> 1) * 64, wn = (wid & 1) * 64;
  int fr = lane & 15, kb = lane >> 4;
  int b = blockIdx.x;
  int xcd = b & 7, r = b >> 3;
  int by = xcd * 4 + (r & 3), bx = r >> 2;
  int q0 = by * 128, l0 = bx * 128;
  f32x4 acc[4][4] = {};
  for (int kt = 0; kt < 128; kt += 64) {
#pragma unroll
    for (int j = 0; j < 4; ++j) {
      int g = wid * 256 + j * 64 + lane;
      int row = g >> 3, s = (g & 7) ^ (row & 7);
      int co = kt + s * 8;
      size_t ldso = (size_t)(wid * 256 + j * 64) * 8;
      gl16(&fh[(size_t)(q0 + row) * 128 + co], Ah + ldso);
      gl16(&fl[(size_t)(q0 + row) * 128 + co], Al + ldso);
      gl16(&bh[(size_t)(l0 + row) * 128 + co], Bh + ldso);
      gl16(&bl[(size_t)(l0 + row) * 128 + co], Bl + ldso);
    }
    __syncthreads();
#pragma unroll
    for (int kf = 0; kf < 2; ++kf) {
      f16x8 ah[4], al4[4], bh4[4], bl4[4];
#pragma unroll
      for (int mi = 0; mi < 4; ++mi) {
        int row = wm + mi * 16 + fr;
        int off = row * 64 + ((kf * 4 + kb) ^ (row & 7)) * 8;
        ah[mi] = *(const f16x8*)&Ah[off];
        al4[mi] = *(const f16x8*)&Al[off];
      }
#pragma unroll
      for (int ni = 0; ni < 4; ++ni) {
        int row = wn + ni * 16 + fr;
        int off = row * 64 + ((kf * 4 + kb) ^ (row & 7)) * 8;
        bh4[ni] = *(const f16x8*)&Bh[off];
        bl4[ni] = *(const f16x8*)&Bl[off];
      }
#pragma unroll
      for (int mi = 0; mi < 4; ++mi)
#pragma unroll
        for (int ni = 0; ni < 4; ++ni) {
          acc[mi][ni] = __builtin_amdgcn_mfma_f32_16x16x32_f16(ah[mi], bh4[ni], acc[mi][ni], 0, 0, 0);
          acc[mi][ni] = __builtin_amdgcn_mfma_f32_16x16x32_f16(ah[mi], bl4[ni], acc[mi][ni], 0, 0, 0);
          acc[mi][ni] = __builtin_amdgcn_mfma_f32_16x16x32_f16(al4[mi], bh4[ni], acc[mi][ni], 0, 0, 0);
        }
    }
    __syncthreads();
  }
  // stage tile to LDS as fp32 [128][128]
  float* TC = (float*)lds;
#pragma unroll
  for (int mi = 0; mi < 4; ++mi) {
    int qr = wm + mi * 16 + kb * 4;
#pragma unroll
    for (int ni = 0; ni < 4; ++ni) {
      int lc = wn + ni * 16 + fr;
#pragma unroll
      for (int r2 = 0; r2 < 4; ++r2)
        TC[(qr + r2) * 128 + lc] = acc[mi][ni][r2];
    }
  }
  __syncthreads();
  // write 255 diagonal segments (contiguous in l) to Rd; 64 diagonals per wave
  int dq0l0 = q0 - l0;
  for (int dd = wid * 64; dd < wid * 64 + 64; ++dd) {
    if (dd >= 255) break;
    int d = dd - 127;
    int jst = d < 0 ? -d : 0;
    int len = 128 - (d < 0 ? -d : d);
    int drow = (dq0l0 + d) & 4095;
#pragma unroll
    for (int ro = 0; ro < 2; ++ro) {
      int j = jst + ro * 64 + lane;
      if (j < jst + len)
        C[(size_t)drow * 4096 + l0 + j] = TC[(j + d) * 128 + j];
    }
  }
}

// ---------------- passA on diagonal layout: 1-D 9-tap row stencil ----------------
// Yd[drow][u] = (sum of masked taps Rd[drow][u+s]) / max(nrm[u],1e-4)
__global__ __launch_bounds__(256) void k_passA(const float* __restrict__ Rd, const float* __restrict__ nrm,
                                               float* __restrict__ Yd) {
  int tid = blockIdx.x * 256 + threadIdx.x;      // 8192 blocks
  int drow = tid >> 9;
  int u0 = (tid & 511) * 8;
  float buf[3][16];
#pragma unroll
  for (int c = 0; c < 3; ++c) {
    int base = drow * 4096 + u0 + (c - 1) * 64 - 4;
#pragma unroll
    for (int kk = 0; kk < 4; ++kk) {
      int a = base + kk * 4;
      a = a < 0 ? 0 : (a > 16777212 ? 16777212 : a);
      *(float4*)&buf[c][kk * 4] = *(const float4*)&Rd[a];
    }
  }
  float4 nv0 = *(const float4*)&nrm[u0];
  float4 nv1 = *(const float4*)&nrm[u0 + 4];
  float nvv[8] = {nv0.x, nv0.y, nv0.z, nv0.w, nv1.x, nv1.y, nv1.z, nv1.w};
  float out[8];
#pragma unroll
  for (int e = 0; e < 8; ++e) {
    int l = u0 + e;
    int q = (drow + l) & 4095;
    int lh = l >> 6, lw = l & 63, qh = q >> 6, qw = q & 63;
    float a = 0.f;
#pragma unroll
    for (int c = 0; c < 3; ++c) {
      bool mh = ((u32)(qh + c - 1) < 64u) && ((u32)(lh + c - 1) < 64u);
#pragma unroll
      for (int d = 0; d < 3; ++d) {
        bool mw = ((u32)(qw + d - 1) < 64u) && ((u32)(lw + d - 1) < 64u);
        if (mh && mw) a += buf[c][e + d + 3];
      }
    }
    out[e] = a / fmaxf(nvv[e], 1e-4f);
  }
  *(float4*)&Yd[(size_t)drow * 4096 + u0] = make_float4(out[0], out[1], out[2], out[3]);
  *(float4*)&Yd[(size_t)drow * 4096 + u0 + 4] = make_float4(out[4], out[5], out[6], out[7]);
}

// ---------------- pbsm on diagonal layout -> row-major fp32 S ----------------
// 512 thr, 8 elem/thread (passA-proven register shape); XCD d-band pinning; ST[64][66].
__global__ __launch_bounds__(512) void k_pbsm(const float* __restrict__ Yd, float* __restrict__ S) {
  __shared__ float ST[64][66];
  int b = blockIdx.x;
  // d-band pinning: xcd = b&7; within xcd, sweep u (r&63) fastest, then d-block (r>>6)
  int xcd = b & 7, r = b >> 3;            // r in [0,512)
  int db = xcd * 8 + (r >> 6);            // d-block [0,64)
  int ub = r & 63;                        // u-block [0,64)
  int d0 = db * 64, u0 = ub * 64;
  int t = threadIdx.x;
  int dl = t >> 3, us = (t & 7) * 8;
  int drow = d0 + dl;
  int l0 = u0 + us;
  int lh = u0 >> 6;
  bool lhok = (lh >= 2 && lh <= 61);
  float buf[3][16];
#pragma unroll
  for (int c = 0; c < 3; ++c) {
    int base = drow * 4096 + l0 + (c - 1) * 64 - 4;
#pragma unroll
    for (int kk = 0; kk < 4; ++kk) {
      int a = base + kk * 4;
      a = a < 0 ? 0 : (a > 16777212 ? 16777212 : a);
      *(float4*)&buf[c][kk * 4] = *(const float4*)&Yd[a];
    }
  }
#pragma unroll
  for (int e = 0; e < 8; ++e) {
    ST[dl][us + e] = (buf[0][e + 3] + buf[0][e + 4] + buf[0][e + 5])
                   + (buf[1][e + 3] + buf[1][e + 4] + buf[1][e + 5])
                   + (buf[2][e + 3] + buf[2][e + 4] + buf[2][e + 5]);
  }
  // edge fixup: only threads whose 8-element span touches a non-interior q (or edge lh)
  int qa = (drow + l0) & 4095, qb = (drow + l0 + 7) & 4095;
  bool anyedge = !lhok || (qa >> 6) < 2 || (qa >> 6) > 61 || (qb >> 6) < 2 || (qb >> 6) > 61 ||
                 (qb != qa + 7);
  if (anyedge) {
    for (int e = 0; e < 8; ++e) {
      int l = l0 + e;
      int q = (drow + l) & 4095;
      int qh = q >> 6;
      if (!(lhok && qh >= 2 && qh <= 61)) {
        // exact reference flat/permuted path
        int pl = ((l & 63) << 6) | (l >> 6);
        int pq = ((q & 63) << 6) | (q >> 6);
        float a = 0.f;
        for (int e2 = -1; e2 <= 1; ++e2) {
          int pa = pl + e2, pb = pq + e2;
          if ((u32)pa < 4096u && (u32)pb < 4096u) {
            int aa0 = ((pa & 63) << 6) | (pa >> 6);
            int bb0 = ((pb & 63) << 6) | (pb >> 6);
            for (int e1 = -1; e1 <= 1; ++e1) {
              int aa = aa0 + e1, bb = bb0 + e1;
              if ((u32)aa < 4096u && (u32)bb < 4096u)
                a += Yd[(size_t)((bb - aa) & 4095) * 4096 + aa];
            }
          }
        }
        ST[dl][us + e] = a;
      }
    }
  }
  __syncthreads();
  // write tile to S row-major: for each j = dl+ul, lanes sweep the segment (coalesced)
  int w2 = t >> 6, lane = t & 63;       // 8 waves x 16 j-values
  for (int jj = 0; jj < 16; ++jj) {
    int j = w2 * 16 + jj;
    if (j >= 127) break;
    int jm = j < 63 ? j : 63;
    int dd = jm - lane;
    int ul = j - dd;
    if (dd >= 0 && ul < 64) {
      int q = (d0 + u0 + j) & 4095;
      S[(size_t)q * 4096 + u0 + ul] = ST[dd][ul];
    }
  }
}

// row softmax over l (SCALE=10), vectorized, fp32 S -> f16 att
__global__ __launch_bounds__(256) void k_softmax(const float* __restrict__ S, u16* __restrict__ att) {
  int q = blockIdx.x, t = threadIdx.x;
  const float* row = S + (size_t)q * 4096;
  float4 v[4];
  float m = -3.4e38f;
#pragma unroll
  for (int i = 0; i < 4; ++i) {
    v[i] = *(const float4*)&row[i * 1024 + t * 4];
    m = fmaxf(m, fmaxf(fmaxf(v[i].x, v[i].y), fmaxf(v[i].z, v[i].w)));
  }
#pragma unroll
  for (int off = 32; off; off >>= 1) m = fmaxf(m, __shfl_xor(m, off));
  __shared__ float redm[4], reds[4];
  int wid = t >> 6, lane = t & 63;
  if (lane == 0) redm[wid] = m;
  __syncthreads();
  m = fmaxf(fmaxf(redm[0], redm[1]), fmaxf(redm[2], redm[3]));
  float s = 0.f;
#pragma unroll
  for (int i = 0; i < 4; ++i) {
    v[i].x = expf(10.f * (v[i].x - m)); v[i].y = expf(10.f * (v[i].y - m));
    v[i].z = expf(10.f * (v[i].z - m)); v[i].w = expf(10.f * (v[i].w - m));
    s += v[i].x + v[i].y + v[i].z + v[i].w;
  }
#pragma unroll
  for (int off = 32; off; off >>= 1) s += __shfl_xor(s, off);
  if (lane == 0) reds[wid] = s;
  __syncthreads();
  s = reds[0] + reds[1] + reds[2] + reds[3];
  float inv = 1.f / s;
  u16* arow = att + (size_t)q * 4096;
#pragma unroll
  for (int i = 0; i < 4; ++i) {
    union { u16 h[4]; uint2 u; } pk;
    pk.h[0] = f2h(v[i].x * inv); pk.h[1] = f2h(v[i].y * inv);
    pk.h[2] = f2h(v[i].z * inv); pk.h[3] = f2h(v[i].w * inv);
    *(uint2*)&arow[i * 1024 + t * 4] = pk.u;
  }
}

// RWt[m][l] = raw_w[l, c,i,j] (m = c*16+i*4+j), f16; 4 l per thread
__global__ void k_rwt(const float* __restrict__ bi, u16* __restrict__ RWt) {
  int tid = blockIdx.x * 256 + threadIdx.x;       // m*1024 + l/4
  int m = tid >> 10, lq = (tid & 1023) * 4;
  int c = m >> 4, i = (m >> 2) & 3, j = m & 3;
  int y = 2 * (lq >> 6) - 1 + i;
  union { u16 h[4]; uint2 u; } pk;
#pragma unroll
  for (int e = 0; e < 4; ++e) {
    int x = 2 * ((lq + e) & 63) - 1 + j;
    float v = 0.f;
    if ((u32)y < 128u && (u32)x < 128u) v = bi[c * 16384 + y * 128 + x];
    pk.h[e] = f2h(v);
  }
  *(uint2*)&RWt[(size_t)m * 4096 + lq] = pk.u;
}

// ---------------- PV GEMM: double-buffered gl16 + XCD m-panel swizzle ----------------
__global__ __launch_bounds__(256) void k_gemm_pv(const u16* __restrict__ A, const u16* __restrict__ Bt,
                                                 float* __restrict__ C) {
  __shared__ u16 lds[2 * 16384];
  int t = threadIdx.x, lane = t & 63, wid = t >> 6;
  int wm = (wid >> 1) * 64, wn = (wid & 1) * 64;
  int fr = lane & 15, kb = lane >> 4;
  int bid = blockIdx.x;
  int my = (bid & 7) * 4 + ((bid >> 3) & 3);
  int nx = bid >> 5;
  int m0 = my * 128, n0 = nx * 128;
  f32x4 acc[4][4] = {};
#define STAGE(buf, kt)                                                                  \
  {                                                                                     \
    u16* lA = lds + (buf) * 16384;                                                      \
    u16* lB = lA + 8192;                                                                \
    _Pragma("unroll")                                                                   \
    for (int j = 0; j < 4; ++j) {                                                       \
      int g = wid * 256 + j * 64 + lane;                                                \
      int row = g >> 3, sw = (g & 7) ^ (row & 7);                                       \
      size_t ldso = (size_t)(wid * 256 + j * 64) * 8;                                   \
      gl16(&A[(size_t)(m0 + row) * 4096 + (kt) + sw * 8], lA + ldso);                   \
      gl16(&Bt[(size_t)(n0 + row) * 4096 + (kt) + sw * 8], lB + ldso);                  \
    }                                                                                   \
  }
  STAGE(0, 0)
  __syncthreads();
  int cur = 0;
  for (int kt = 0; kt < 4096; kt += 64) {
    if (kt + 64 < 4096) STAGE(cur ^ 1, kt + 64)
    u16* la = lds + cur * 16384;
    u16* lb = la + 8192;
#pragma unroll
    for (int ks = 0; ks < 2; ++ks) {
      f16x8 af[4], bfr[4];
#pragma unroll
      for (int mi = 0; mi < 4; ++mi) {
        int row = wm + mi * 16 + fr;
        af[mi] = *(const f16x8*)&la[row * 64 + ((ks * 32 + kb * 8) ^ ((row & 7) << 3))];
      }
#pragma unroll
      for (int ni = 0; ni < 4; ++ni) {
        int row = wn + ni * 16 + fr;
        bfr[ni] = *(const f16x8*)&lb[row * 64 + ((ks * 32 + kb * 8) ^ ((row & 7) << 3))];
      }
#pragma unroll
      for (int mi = 0; mi < 4; ++mi)
#pragma unroll
        for (int ni = 0; ni < 4; ++ni)
          acc[mi][ni] = __builtin_amdgcn_mfma_f32_16x16x32_f16(af[mi], bfr[ni], acc[mi][ni], 0, 0, 0);
    }
    __syncthreads();
    cur ^= 1;
  }
#undef STAGE
#pragma unroll
  for (int mi = 0; mi < 4; ++mi) {
    int mr = m0 + wm + mi * 16 + kb * 4;
#pragma unroll
    for (int ni = 0; ni < 4; ++ni) {
      int nc = n0 + wn + ni * 16 + fr;
#pragma unroll
      for (int r = 0; r < 4; ++r)
        C[(size_t)(mr + r) * 2048 + nc] = acc[mi][ni][r];
    }
  }
}

// stride-2 overlap-add of 4x4 patches, /4 -> HWC f16; XCD-pinned to match gemm_pv m-panels
__global__ void k_overlap(const float* __restrict__ O, u16* __restrict__ Yh) {
  int b = blockIdx.x;
  int xcd = b & 7, r = b >> 3;
  int oypair = xcd * 8 + (r & 7);
  int c = r >> 3;
  int t = threadIdx.x;
  int idx = c * 16384 + oypair * 256 + t;
  int ox = idx & 127, oy = (idx & 16383) >> 7;
  int py = oy + 1, px = ox + 1;
  float s = 0.f;
#pragma unroll
  for (int di = 0; di < 2; ++di) {
    int i = (py & 1) + 2 * di;
    int hs = (py - i) >> 1;
    if ((u32)hs >= 64u) continue;
#pragma unroll
    for (int dj = 0; dj < 2; ++dj) {
      int j = (px & 1) + 2 * dj;
      int wsx = (px - j) >> 1;
      if ((u32)wsx >= 64u) continue;
      s += O[(size_t)(hs * 64 + wsx) * 2048 + c * 16 + i * 4 + j];
    }
  }
  Yh[((size_t)oy * 128 + ox) * 128 + c] = f2h(0.25f * s);
}

// ---------------- conv: HWC f16 in, implicit GEMM, global_load_lds ----------------
template<int OUT_F16>
__global__ __launch_bounds__(256) void k_conv(const u16* __restrict__ In, const u16* __restrict__ Wp,
                                              const float* __restrict__ bias, void* __restrict__ out_,
                                              const u16* __restrict__ zg) {
  __shared__ u16 lds[2 * 128 * 64];
  u16* la = lds; u16* lb = lds + 8192;
  int t = threadIdx.x, lane = t & 63, wid = t >> 6;
  int wm = (wid >> 1) * 64, wn = (wid & 1) * 64;
  int fr = lane & 15, kb = lane >> 4;
  int yrow = blockIdx.x, bidx = blockIdx.y;
  const u16* inH = In + (size_t)bidx * 2097152;
  f32x4 acc[4][4] = {};
  for (int step = 0; step < 18; ++step) {
    int tap = step >> 1, ci0 = (step & 1) * 64;
    int dy = tap / 3, dx = tap - 3 * (tap / 3);
    int y = yrow + dy - 1;
#pragma unroll
    for (int j = 0; j < 4; ++j) {
      int g = wid * 256 + j * 64 + lane;
      int row = g >> 3, s = (g & 7) ^ (row & 7);
      size_t ldso = (size_t)(wid * 256 + j * 64) * 8;
      gl16(&Wp[(size_t)row * 1152 + step * 64 + s * 8], la + ldso);
      int xx = row + dx - 1;
      const u16* src = ((u32)y < 128u && (u32)xx < 128u)
                         ? &inH[((size_t)y * 128 + xx) * 128 + ci0 + s * 8] : zg;
      gl16(src, lb + ldso);
    }
    __syncthreads();
#pragma unroll
    for (int ks = 0; ks < 2; ++ks) {
      f16x8 af[4], bfr[4];
#pragma unroll
      for (int mi = 0; mi < 4; ++mi) {
        int row = wm + mi * 16 + fr;
        af[mi] = *(const f16x8*)&la[row * 64 + ((ks * 32 + kb * 8) ^ ((row & 7) << 3))];
      }
#pragma unroll
      for (int ni = 0; ni < 4; ++ni) {
        int row = wn + ni * 16 + fr;
        bfr[ni] = *(const f16x8*)&lb[row * 64 + ((ks * 32 + kb * 8) ^ ((row & 7) << 3))];
      }
#pragma unroll
      for (int mi = 0; mi < 4; ++mi)
#pragma unroll
        for (int ni = 0; ni < 4; ++ni)
          acc[mi][ni] = __builtin_amdgcn_mfma_f32_16x16x32_f16(af[mi], bfr[ni], acc[mi][ni], 0, 0, 0);
    }
    __syncthreads();
  }
#pragma unroll
  for (int mi = 0; mi < 4; ++mi) {
    int co = wm + mi * 16 + kb * 4;
#pragma unroll
    for (int ni = 0; ni < 4; ++ni) {
      int x = wn + ni * 16 + fr;
      if (OUT_F16) {
        union { u16 h[4]; uint2 v; } pk;
#pragma unroll
        for (int r = 0; r < 4; ++r) {
          float val = acc[mi][ni][r] + bias[co + r];
          val = val > 0.f ? val : expm1f(val);
          pk.h[r] = f2h(val);
        }
        u16* oH = (u16*)out_ + (size_t)bidx * 2097152;
        *(uint2*)&oH[((size_t)yrow * 128 + x) * 128 + co] = pk.v;
      } else {
        float* oF = (float*)out_ + (size_t)bidx * 2097152;
#pragma unroll
        for (int r = 0; r < 4; ++r) {
          float val = acc[mi][ni][r] + bias[co + r];
          val = val > 0.f ? val : expm1f(val);
          oF[(size_t)(co + r) * 16384 + yrow * 128 + x] = val;
        }
      }
    }
  }
}

// ---------------- host ----------------

extern "C" void kernel_launch(void* const* d_in, const int* in_sizes, int n_in,
                              void* d_out, int out_size, void* d_ws, size_t ws_size,
                              hipStream_t stream) {
  const float* f  = (const float*)d_in[0];
  const float* b  = (const float*)d_in[1];
  const float* w1 = (const float*)d_in[2];
  const float* b1 = (const float*)d_in[3];
  const float* w2 = (const float*)d_in[4];
  const float* b2 = (const float*)d_in[5];
  float* out = (float*)d_out;
  char* ws = (char*)d_ws;

  // workspace layout (155,795,456 B total)
  float* S0   = (float*)(ws);                       // 64MB: Rd -> S (scores) -> O [0,32) / Z1h
  float* S1   = (float*)(ws + 67108864);            // 64MB: Yd -> att [0,32) + RWt [32,48)
  u16*   fsTh = (u16*)(ws + 134217728);             // 1,048,576
  u16*   fsTl = (u16*)(ws + 135266304);             // 1,048,576
  u16*   bsTh = (u16*)(ws + 136314880);             // 1,048,576
  u16*   bsTl = (u16*)(ws + 137363456);             // 1,048,576
  float* nrm  = (float*)(ws + 138412032);           // 16,384
  u16*   Yh   = (u16*)(ws + 138428416);             // 16,777,216 (4 batches HWC f16)
  u16*   Wp1  = (u16*)(ws + 155205632);             // 294,912
  u16*   Wp2  = (u16*)(ws + 155500544);             // 294,912 -> 155,795,456
  float* Rd   = S0;                                 // diag R, full 64MB
  float* Yd   = S1;                                 // diag Y0, full 64MB
  float* Ssc  = S0;                                 // fp32 scores, overlays Rd (dead)
  u16*   att  = (u16*)S1;                           // [0,32MB) of S1 (Yd dead after pbsm)
  u16*   RWt  = (u16*)(ws + 67108864 + 33554432);   // [32,48MB) of S1
  float* O    = S0;                                 // [0,32MB) of S0 (Ssc dead after softmax)
  u16*   Z1h  = (u16*)S0;                           // convs after loop
  u16*   zg   = (u16*)(ws + 50331648);              // 256 B zero guard (memset after last producer)

  k_wperm<<<576, 256, 0, stream>>>(w1, Wp1);
  k_wperm<<<576, 256, 0, stream>>>(w2, Wp2);

  for (int i = 0; i < 4; ++i) {
    const float* fb = f + (size_t)i * 2097152;
    const float* bb = b + (size_t)i * 2097152;
    k_extract<<<64, 256, 0, stream>>>(fb, bb, fsTh, fsTl, bsTh, bsTl);
    k_norm<<<1024, 256, 0, stream>>>(bsTh, bsTl, nrm);
    k_rgemm<<<1024, 256, 0, stream>>>(fsTh, fsTl, bsTh, bsTl, Rd);
    k_passA<<<8192, 256, 0, stream>>>(Rd, nrm, Yd);
    k_pbsm<<<4096, 512, 0, stream>>>(Yd, Ssc);
    k_softmax<<<4096, 256, 0, stream>>>(Ssc, att);
    k_rwt<<<8192, 256, 0, stream>>>(bb, RWt);
    k_gemm_pv<<<512, 256, 0, stream>>>(att, RWt, O);
    k_overlap<<<8192, 256, 0, stream>>>(O, Yh + (size_t)i * 2097152);
  }

  hipMemsetAsync(zg, 0, 256, stream);
  k_conv<1><<<dim3(128, 4), 256, 0, stream>>>(Yh, Wp1, b1, Z1h, zg);
  k_conv<0><<<dim3(128, 4), 256, 0, stream>>>(Z1h, Wp2, b2, out, zg);

  (void)in_sizes; (void)n_in; (void)out_size; (void)ws_size;
}